// Round 1
// baseline (22875.278 us; speedup 1.0000x reference)
//
#include <hip/hip_runtime.h>

// RNN echo-state scan on MI355X.
// h_{t+1}[b,n] = sum_k tanh(h_t)[b,k]*W_hh[n,k] + sum_i x[b,t,i]*W_ih[n,i] + noise[t,n]*1e-3
// Outputs: out[0 .. NREC*T) = h_t[63,:] transposed to [NREC][T]; then h_last [B][NREC].
//
// Structure: 2 independent batch-groups (32 batches each) x 32 WGs (32 output cols each).
// Per-group flag barrier per step; W (hi/lo bf16) LDS-resident; split-bf16 3-pass MFMA
// for ~fp32 accuracy (edge-of-chaos dynamics make single-bf16 W too risky).

#define TT    2048
#define BB    64
#define NIN   64
#define NRECN 1024
#define KTOT  1088      // 1024 (tanh h) + 64 (x)
#define NTHC  32        // 32-wide K chunks covering the th part
#define MT    32        // batches per group
#define NT    32        // output cols per WG
#define NGRP  2         // 64 / MT
#define WPG   32        // WGs per group = 1024 / NT
#define NWG   (NGRP * WPG)
#define WPAD  1096      // LDS row pitch (bf16 elems): 1088 + 8 -> 2192B, 16B aligned, 2-way-max bank alias
#define NOISE_STD 0.001f

typedef __attribute__((ext_vector_type(8))) short short8;
typedef __attribute__((ext_vector_type(4))) float f32x4;

__device__ __forceinline__ unsigned short f2bf(float f) {
  unsigned u = __float_as_uint(f);
  u += 0x7FFFu + ((u >> 16) & 1u);   // round-to-nearest-even to bf16
  return (unsigned short)(u >> 16);
}
__device__ __forceinline__ float bf2f(unsigned short h) {
  return __uint_as_float(((unsigned)h) << 16);
}

__global__ __launch_bounds__(256, 1) void rnn_scan_kernel(
    const float* __restrict__ x, const float* __restrict__ W_ih,
    const float* __restrict__ W_hh, const float* __restrict__ noise,
    float* __restrict__ out, int* __restrict__ flags,
    unsigned short* __restrict__ th_hi, unsigned short* __restrict__ th_lo)
{
  extern __shared__ unsigned short smem[];
  unsigned short* w_hi = smem;              // [NT][WPAD]
  unsigned short* w_lo = smem + NT * WPAD;  // [NT][WPAD]

  const int wg   = blockIdx.x;
  const int gm   = wg / WPG;      // batch group 0..1
  const int gn   = wg % WPG;      // col tile    0..31
  const int tid  = threadIdx.x;
  const int lane = tid & 63;
  const int wv   = tid >> 6;      // wave 0..3
  const int msub = wv >> 1;       // m sub-tile 0..1
  const int nsub = wv & 1;        // n sub-tile 0..1
  const int l15  = lane & 15;
  const int lk8  = (lane >> 4) * 8;

  // ---- one-time: stage W slice (rows gn*NT..+NT, K=1088) into LDS as hi/lo bf16
  for (int idx = tid; idx < NT * KTOT; idx += 256) {
    int nr = idx / KTOT;
    int k  = idx - nr * KTOT;
    int ng = gn * NT + nr;
    float v = (k < NRECN) ? W_hh[(size_t)ng * NRECN + k]
                          : W_ih[(size_t)ng * NIN + (k - NRECN)];
    unsigned short h = f2bf(v);
    unsigned short l = f2bf(v - bf2f(h));
    w_hi[nr * WPAD + k] = h;
    w_lo[nr * WPAD + k] = l;
  }
  __syncthreads();

  int* flags_g = flags + gm * WPG;

  const int mloc   = msub * 16 + l15;        // local m (A-frag row)
  const int nloc   = nsub * 16 + l15;        // local n (B-frag row in W slice)
  const int b_glob = gm * MT + mloc;         // global batch of A-frag row
  const int n_glob = gn * NT + nloc;         // global output col
  const unsigned short* whp = w_hi + nloc * WPAD + lk8;
  const unsigned short* wlp = w_lo + nloc * WPAD + lk8;
  const int grp_off = gm * 2 * MT * NRECN;   // th arrays: [NGRP][2][MT][NRECN]

  for (int t = 0; t < TT; ++t) {
    const int buf = t & 1;
    if (t > 0) {
      if (wv == 0) {
        if (lane < WPG) {
          while (__hip_atomic_load(&flags_g[lane], __ATOMIC_RELAXED,
                                   __HIP_MEMORY_SCOPE_AGENT) < t) {
            __builtin_amdgcn_s_sleep(1);
          }
        }
        __builtin_amdgcn_fence(__ATOMIC_ACQUIRE, "agent");  // buffer_inv: see fresh th
      }
      __syncthreads();
    }

    f32x4 acc1 = {0.f, 0.f, 0.f, 0.f};
    f32x4 acc2 = {0.f, 0.f, 0.f, 0.f};

    if (t > 0) {
      const unsigned short* ah_p = th_hi + grp_off + buf * MT * NRECN + mloc * NRECN + lk8;
      const unsigned short* al_p = th_lo + grp_off + buf * MT * NRECN + mloc * NRECN + lk8;
      #pragma unroll
      for (int c = 0; c < NTHC; ++c) {
        short8 ah = *(const short8*)(ah_p + c * 32);
        short8 al = *(const short8*)(al_p + c * 32);
        short8 bh = *(const short8*)(whp + c * 32);
        short8 bl = *(const short8*)(wlp + c * 32);
        acc1 = __builtin_amdgcn_mfma_f32_16x16x32_bf16(ah, bh, acc1, 0, 0, 0);
        acc2 = __builtin_amdgcn_mfma_f32_16x16x32_bf16(al, bh, acc2, 0, 0, 0);
        acc2 = __builtin_amdgcn_mfma_f32_16x16x32_bf16(ah, bl, acc2, 0, 0, 0);
      }
    }

    // x part (K chunks 32,33): fold input projection into the same GEMM
    {
      const float* xp = x + ((size_t)b_glob * TT + t) * NIN + lk8;
      #pragma unroll
      for (int c2 = 0; c2 < 2; ++c2) {
        f32x4 v0 = *(const f32x4*)(xp + c2 * 32);
        f32x4 v1 = *(const f32x4*)(xp + c2 * 32 + 4);
        short8 ah, al;
        #pragma unroll
        for (int j = 0; j < 4; ++j) {
          float v = v0[j];
          unsigned short h = f2bf(v);
          ah[j] = (short)h; al[j] = (short)f2bf(v - bf2f(h));
        }
        #pragma unroll
        for (int j = 0; j < 4; ++j) {
          float v = v1[j];
          unsigned short h = f2bf(v);
          ah[4 + j] = (short)h; al[4 + j] = (short)f2bf(v - bf2f(h));
        }
        const int kk = NRECN + c2 * 32;
        short8 bh = *(const short8*)(whp + kk);
        short8 bl = *(const short8*)(wlp + kk);
        acc1 = __builtin_amdgcn_mfma_f32_16x16x32_bf16(ah, bh, acc1, 0, 0, 0);
        acc2 = __builtin_amdgcn_mfma_f32_16x16x32_bf16(al, bh, acc2, 0, 0, 0);
        acc2 = __builtin_amdgcn_mfma_f32_16x16x32_bf16(ah, bl, acc2, 0, 0, 0);
      }
    }

    // epilogue: + noise, outputs, tanh -> split hi/lo -> next th buffer
    const float nz = noise[(size_t)t * NRECN + n_glob] * NOISE_STD;
    const int nbuf = (t + 1) & 1;
    unsigned short* oh = th_hi + grp_off + nbuf * MT * NRECN;
    unsigned short* ol = th_lo + grp_off + nbuf * MT * NRECN;
    #pragma unroll
    for (int r = 0; r < 4; ++r) {
      const int mr = msub * 16 + (lane >> 4) * 4 + r;  // local m (C-frag row, m89 layout)
      const int br = gm * MT + mr;                     // global batch
      float h = acc1[r] + acc2[r] + nz;
      if (br == BB - 1) out[(size_t)n_glob * TT + t] = h;
      if (t == TT - 1) out[(size_t)NRECN * TT + (size_t)br * NRECN + n_glob] = h;
      float e  = __expf(2.f * h);
      float th = 1.f - 2.f / (e + 1.f);                // tanh(h), safe at +/-inf
      unsigned short hh = f2bf(th);
      unsigned short hl = f2bf(th - bf2f(hh));
      oh[mr * NRECN + n_glob] = hh;
      ol[mr * NRECN + n_glob] = hl;
    }
    __syncthreads();                                   // drains all waves' stores to L2
    if (tid == 0) {
      __builtin_amdgcn_fence(__ATOMIC_RELEASE, "agent");  // wbl2: publish th tile
      __hip_atomic_store(&flags_g[gn], t + 1, __ATOMIC_RELAXED,
                         __HIP_MEMORY_SCOPE_AGENT);
    }
  }
}

extern "C" void kernel_launch(void* const* d_in, const int* in_sizes, int n_in,
                              void* d_out, int out_size, void* d_ws, size_t ws_size,
                              hipStream_t stream) {
  const float* x     = (const float*)d_in[0];
  const float* W_ih  = (const float*)d_in[1];
  const float* W_hh  = (const float*)d_in[2];
  const float* noise = (const float*)d_in[3];
  float* out = (float*)d_out;

  char* ws = (char*)d_ws;
  int* flags = (int*)ws;                                   // 64 flags (+pad to 1KB)
  unsigned short* th_hi = (unsigned short*)(ws + 1024);    // [2][2][32][1024] bf16
  unsigned short* th_lo = th_hi + NGRP * 2 * MT * NRECN;   // same size
  // ws usage: 1024 + 2*262144 = 525,312 bytes

  // Stream-ordered flag reset -> deterministic across graph replays.
  (void)hipMemsetAsync(flags, 0, 1024, stream);

  const size_t lds_bytes = (size_t)2 * NT * WPAD * sizeof(unsigned short); // 140,288
  (void)hipFuncSetAttribute((const void*)rnn_scan_kernel,
                            hipFuncAttributeMaxDynamicSharedMemorySize,
                            (int)lds_bytes);

  rnn_scan_kernel<<<dim3(NWG), dim3(256), lds_bytes, stream>>>(
      x, W_ih, W_hh, noise, out, flags, th_hi, th_lo);
}

// Round 2
// 18544.099 us; speedup vs baseline: 1.2336x; 1.2336x over previous
//
#include <hip/hip_runtime.h>

// RNN echo-state scan on MI355X — round 2.
// h_{t+1}[b,n] = sum_k tanh(h_t)[b,k]*W_hh[n,k] + x_t[b]·W_ih[n] + noise[t,n]*1e-3
// 2 batch-groups x 32 WGs (32 cols each). Cross-WG exchange of tanh(h) via
// write-through (sc1) stores to MALL + per-step flag barrier; consumers do
// acquire-inv + cached loads. No release-side buffer_wbl2 (that was round 1's
// 11 us/step killer). W hi/lo bf16 LDS-resident, chunk-major conflict-free.

#define TT    2048
#define BB    64
#define NIN   64
#define NRECN 1024
#define KTOT  1088
#define MT    32
#define NT    32
#define NGRP  2
#define WPG   32
#define NWG   (NGRP * WPG)
#define NOISE_STD 0.001f

typedef __attribute__((ext_vector_type(8))) short short8;
typedef __attribute__((ext_vector_type(4))) float f32x4;

__device__ __forceinline__ unsigned short f2bf(float f) {
  unsigned u = __float_as_uint(f);
  u += 0x7FFFu + ((u >> 16) & 1u);   // RNE to bf16
  return (unsigned short)(u >> 16);
}
__device__ __forceinline__ float bf2f(unsigned short h) {
  return __uint_as_float(((unsigned)h) << 16);
}
// Write-through, agent-coherent 2B store (reaches MALL; never dirty in L2).
__device__ __forceinline__ void st_b16_sc1(unsigned short* p, unsigned short v) {
  unsigned vv = v;
  asm volatile("global_store_short %0, %1, off sc1" :: "v"(p), "v"(vv) : "memory");
}
__device__ __forceinline__ void split8(const f32x4& v0, const f32x4& v1,
                                       short8& ah, short8& al) {
  #pragma unroll
  for (int j = 0; j < 4; ++j) {
    unsigned short h = f2bf(v0[j]);
    ah[j] = (short)h; al[j] = (short)f2bf(v0[j] - bf2f(h));
  }
  #pragma unroll
  for (int j = 0; j < 4; ++j) {
    unsigned short h = f2bf(v1[j]);
    ah[4 + j] = (short)h; al[4 + j] = (short)f2bf(v1[j] - bf2f(h));
  }
}

__global__ __launch_bounds__(256, 1) void rnn_scan_kernel(
    const float* __restrict__ x, const float* __restrict__ W_ih,
    const float* __restrict__ W_hh, const float* __restrict__ noise,
    float* __restrict__ out, int* __restrict__ flags,
    unsigned short* __restrict__ th_hi, unsigned short* __restrict__ th_lo)
{
  extern __shared__ unsigned short smem[];
  unsigned short* w_hi = smem;                      // chunk-major [KTOT/8][NT][8]
  unsigned short* w_lo = smem + KTOT * NT;

  const int wg = blockIdx.x, gm = wg / WPG, gn = wg % WPG;
  const int tid = threadIdx.x, lane = tid & 63, wv = tid >> 6;
  const int msub = wv >> 1, nsub = wv & 1;
  const int l15 = lane & 15, g4 = lane >> 4, lk8 = g4 * 8;

  // one-time: W slice -> LDS, hi/lo bf16, layout idx = (k>>3)*256 + row*8 + (k&7)
  for (int idx = tid; idx < NT * KTOT; idx += 256) {
    int nr = idx / KTOT, k = idx - nr * KTOT;
    int ng = gn * NT + nr;
    float v = (k < NRECN) ? W_hh[(size_t)ng * NRECN + k]
                          : W_ih[(size_t)ng * NIN + (k - NRECN)];
    unsigned short h = f2bf(v);
    unsigned short l = f2bf(v - bf2f(h));
    int widx = (k >> 3) * (NT * 8) + nr * 8 + (k & 7);
    w_hi[widx] = h; w_lo[widx] = l;
  }
  __syncthreads();

  int* flags_g = flags + gm * 64;                   // groups 256B apart
  const int mloc = msub * 16 + l15;
  const int nloc = nsub * 16 + l15;
  const int b_glob = gm * MT + mloc;
  const int n_glob = gn * NT + nloc;
  const unsigned short* whp = w_hi + g4 * 256 + nloc * 8;  // + c*1024 per chunk
  const unsigned short* wlp = w_lo + g4 * 256 + nloc * 8;
  const int grp_off = gm * 2 * MT * NRECN;
  const float* xrow = x + (size_t)b_glob * TT * NIN;

  f32x4 xv0, xv1, xv2, xv3;
  f32x4 xn0 = {0,0,0,0}, xn1 = {0,0,0,0}, xn2 = {0,0,0,0}, xn3 = {0,0,0,0};
  { const float* xp = xrow + lk8;
    xv0 = *(const f32x4*)xp;        xv1 = *(const f32x4*)(xp + 4);
    xv2 = *(const f32x4*)(xp + 32); xv3 = *(const f32x4*)(xp + 36); }
  float nzv = noise[n_glob] * NOISE_STD, nzn = 0.f;

  for (int t = 0; t < TT; ++t) {
    const int buf = t & 1;
    // ---- wait for all producers of step t-1 (wave0 only), acquire-inv
    if (t > 0 && wv == 0) {
      if (lane < WPG) {
        while (__hip_atomic_load(&flags_g[lane], __ATOMIC_RELAXED,
                                 __HIP_MEMORY_SCOPE_AGENT) < t) { }
      }
      __builtin_amdgcn_fence(__ATOMIC_ACQUIRE, "agent");  // buffer_inv (no wb)
    }

    f32x4 h0 = {0,0,0,0}, h1 = {0,0,0,0}, l0 = {0,0,0,0},
          l1 = {0,0,0,0}, m0 = {0,0,0,0}, m1 = {0,0,0,0};

    // ---- x part (chunks 32,33) — no dependency on peers, overlaps the poll
    {
      short8 ah, al;
      split8(xv0, xv1, ah, al);
      short8 bh = *(const short8*)(whp + 32 * 1024);
      short8 bl = *(const short8*)(wlp + 32 * 1024);
      h0 = __builtin_amdgcn_mfma_f32_16x16x32_bf16(ah, bh, h0, 0, 0, 0);
      l0 = __builtin_amdgcn_mfma_f32_16x16x32_bf16(al, bh, l0, 0, 0, 0);
      m0 = __builtin_amdgcn_mfma_f32_16x16x32_bf16(ah, bl, m0, 0, 0, 0);
      split8(xv2, xv3, ah, al);
      bh = *(const short8*)(whp + 33 * 1024);
      bl = *(const short8*)(wlp + 33 * 1024);
      h1 = __builtin_amdgcn_mfma_f32_16x16x32_bf16(ah, bh, h1, 0, 0, 0);
      l1 = __builtin_amdgcn_mfma_f32_16x16x32_bf16(al, bh, l1, 0, 0, 0);
      m1 = __builtin_amdgcn_mfma_f32_16x16x32_bf16(ah, bl, m1, 0, 0, 0);
    }

    // ---- recurrent part: 32 K-chunks of tanh(h_{t-1}) x W_hh
    if (t > 0) {
      __syncthreads();   // wave0 has inv'd; all waves now see fresh th
      const unsigned short* ah_p =
          th_hi + grp_off + buf * MT * NRECN + mloc * NRECN + lk8;
      const unsigned short* al_p =
          th_lo + grp_off + buf * MT * NRECN + mloc * NRECN + lk8;
      #pragma unroll
      for (int c = 0; c < 32; c += 2) {
        short8 a0  = *(const short8*)(ah_p + c * 32);
        short8 q0  = *(const short8*)(al_p + c * 32);
        short8 b0h = *(const short8*)(whp + c * 1024);
        short8 b0l = *(const short8*)(wlp + c * 1024);
        h0 = __builtin_amdgcn_mfma_f32_16x16x32_bf16(a0, b0h, h0, 0, 0, 0);
        l0 = __builtin_amdgcn_mfma_f32_16x16x32_bf16(q0, b0h, l0, 0, 0, 0);
        m0 = __builtin_amdgcn_mfma_f32_16x16x32_bf16(a0, b0l, m0, 0, 0, 0);
        short8 a1  = *(const short8*)(ah_p + (c + 1) * 32);
        short8 q1  = *(const short8*)(al_p + (c + 1) * 32);
        short8 b1h = *(const short8*)(whp + (c + 1) * 1024);
        short8 b1l = *(const short8*)(wlp + (c + 1) * 1024);
        h1 = __builtin_amdgcn_mfma_f32_16x16x32_bf16(a1, b1h, h1, 0, 0, 0);
        l1 = __builtin_amdgcn_mfma_f32_16x16x32_bf16(q1, b1h, l1, 0, 0, 0);
        m1 = __builtin_amdgcn_mfma_f32_16x16x32_bf16(a1, b1l, m1, 0, 0, 0);
      }
    }

    // ---- epilogue: h, tanh, split, write-through publish
    f32x4 hs = ((h0 + h1) + (l0 + l1)) + (m0 + m1);
    const int nbuf = (t + 1) & 1;
    unsigned short* oh = th_hi + grp_off + nbuf * MT * NRECN;
    unsigned short* ol = th_lo + grp_off + nbuf * MT * NRECN;
    float hout[4];
    #pragma unroll
    for (int r = 0; r < 4; ++r) {
      const int mr = msub * 16 + g4 * 4 + r;       // C-frag row (m89 layout)
      float h = hs[r] + nzv;
      hout[r] = h;
      float e  = __expf(2.f * h);
      float th = 1.f - 2.f / (e + 1.f);
      unsigned short hh = f2bf(th);
      unsigned short hl = f2bf(th - bf2f(hh));
      st_b16_sc1(oh + mr * NRECN + n_glob, hh);
      st_b16_sc1(ol + mr * NRECN + n_glob, hl);
    }
    __syncthreads();   // drains vmcnt(0) in every wave -> th visible at MALL
    if (tid == 0)
      __hip_atomic_store(&flags_g[gn], t + 1, __ATOMIC_RELAXED,
                         __HIP_MEMORY_SCOPE_AGENT);

    // ---- prefetch x/noise for t+1 (completes during next poll window)
    if (t + 1 < TT) {
      const float* xp = xrow + (size_t)(t + 1) * NIN + lk8;
      xn0 = *(const f32x4*)xp;        xn1 = *(const f32x4*)(xp + 4);
      xn2 = *(const f32x4*)(xp + 32); xn3 = *(const f32x4*)(xp + 36);
      nzn = noise[(size_t)(t + 1) * NRECN + n_glob] * NOISE_STD;
    }

    // ---- outputs (off the critical path, after flag post)
    #pragma unroll
    for (int r = 0; r < 4; ++r) {
      const int mr = msub * 16 + g4 * 4 + r;
      const int br = gm * MT + mr;
      if (br == BB - 1) out[(size_t)n_glob * TT + t] = hout[r];
      if (t == TT - 1)
        out[(size_t)NRECN * TT + (size_t)br * NRECN + n_glob] = hout[r];
    }
    xv0 = xn0; xv1 = xn1; xv2 = xn2; xv3 = xn3; nzv = nzn;
  }
}

extern "C" void kernel_launch(void* const* d_in, const int* in_sizes, int n_in,
                              void* d_out, int out_size, void* d_ws, size_t ws_size,
                              hipStream_t stream) {
  const float* x     = (const float*)d_in[0];
  const float* W_ih  = (const float*)d_in[1];
  const float* W_hh  = (const float*)d_in[2];
  const float* noise = (const float*)d_in[3];
  float* out = (float*)d_out;

  char* ws = (char*)d_ws;
  int* flags = (int*)ws;                                   // 2 groups, 256B apart
  unsigned short* th_hi = (unsigned short*)(ws + 1024);    // [2][2][32][1024] bf16
  unsigned short* th_lo = th_hi + NGRP * 2 * MT * NRECN;
  // ws usage: 1024 + 2*262144 = 525,312 bytes

  (void)hipMemsetAsync(flags, 0, 1024, stream);            // deterministic replays

  const size_t lds_bytes = (size_t)2 * KTOT * NT * sizeof(unsigned short); // 139,264
  (void)hipFuncSetAttribute((const void*)rnn_scan_kernel,
                            hipFuncAttributeMaxDynamicSharedMemorySize,
                            (int)lds_bytes);

  rnn_scan_kernel<<<dim3(NWG), dim3(256), lds_bytes, stream>>>(
      x, W_ih, W_hh, noise, out, flags, th_hi, th_lo);
}